// Round 7
// baseline (38.115 us; speedup 1.0000x reference)
//
#include <hip/hip_runtime.h>

// out[chw] = sum_b (prev_x[b,chw] > 0) * popcount_pos(curr_x[b])
//   prev_x: [128, 256, 28, 28] f32, curr_x: [128, 512, 14, 14] f32
// All values integer <= 128*100352 < 2^24 -> exact in fp32 in any order.
//
// R7: isolate the request-count axis. k2 keeps R6's concurrency (392 blocks
// x 256 thr = 6.1 waves/CU) but moves to float4 (16 B/lane, 1 KB/wave-request,
// half of R6's request count) by splitting the 128-batch loop across thread
// pairs (t and t+128 own batch halves of the same column) with an LDS combine.
// If flat vs R6's 29.89 us: ILP, width, and concurrency axes are all null ->
// ~5.4 TB/s is the service ceiling for this read-dominant pattern.

constexpr int NB       = 128;
constexpr int CURR_CHW = 512 * 14 * 14;    // 100352 floats per batch
constexpr int PREV_CHW = 256 * 28 * 28;    // 200704 floats per batch
constexpr int CURR_V4  = CURR_CHW / 4;     // 25088 float4 per batch
constexpr int NSLICE   = 8;                // k1 slices per batch
constexpr int SLICE_V4 = CURR_V4 / NSLICE; // 3136 float4 per (batch, slice)
constexpr int PREV_V4  = PREV_CHW / 4;     // 50176 float4 columns

// Kernel 1: partial positive-count of curr_x. grid = (128, 8) = 1024 blocks.
__global__ void __launch_bounds__(256)
count_pos_kernel(const float* __restrict__ curr, float* __restrict__ partial) {
    const int b = blockIdx.x, q = blockIdx.y;
    const float4* p = reinterpret_cast<const float4*>(curr)
                      + (size_t)b * CURR_V4 + (size_t)q * SLICE_V4;
    int cnt = 0;
    for (int i = threadIdx.x; i < SLICE_V4; i += 256) {
        const float4 v = p[i];
        cnt += (v.x > 0.f) + (v.y > 0.f) + (v.z > 0.f) + (v.w > 0.f);
    }
    #pragma unroll
    for (int off = 32; off > 0; off >>= 1)
        cnt += __shfl_down(cnt, off, 64);
    __shared__ int wsum[4];
    if ((threadIdx.x & 63) == 0) wsum[threadIdx.x >> 6] = cnt;
    __syncthreads();
    if (threadIdx.x == 0)
        partial[q * NB + b] = (float)(wsum[0] + wsum[1] + wsum[2] + wsum[3]);
}

// Kernel 2: out[chw] = sum_b (prev>0) * s_sum[b].
// 392 blocks x 256 threads. Threads t<128 and t>=128 pair up on float4
// column u = blk*128 + (t&127): lower half does batches 0..63, upper half
// 64..127; combine via LDS; lower half stores. 16 B/lane coalesced loads,
// unroll 32 -> 512 B in flight per thread.
__global__ void __launch_bounds__(256)
corr_kernel(const float* __restrict__ prev, const float* __restrict__ partial,
            float* __restrict__ out) {
    __shared__ float s_sum[NB];
    const int t = threadIdx.x;
    if (t < NB) {
        float s = 0.f;
        #pragma unroll
        for (int q = 0; q < NSLICE; ++q)
            s += partial[q * NB + t];
        s_sum[t] = s;
    }
    __syncthreads();

    const int u    = blockIdx.x * 128 + (t & 127);  // float4 column, 0..50175
    const int half = t >> 7;                        // 0 or 1 (batch half)
    const float4* pv = reinterpret_cast<const float4*>(prev)
                       + (size_t)(half * 64) * PREV_V4 + u;

    float4 acc = make_float4(0.f, 0.f, 0.f, 0.f);
    #pragma unroll 32
    for (int b = 0; b < 64; ++b) {
        const float4 v = pv[(size_t)b * PREV_V4];   // coalesced 16 B/lane
        const float s = s_sum[half * 64 + b];       // wave-uniform broadcast
        acc.x += (v.x > 0.f) ? s : 0.f;
        acc.y += (v.y > 0.f) ? s : 0.f;
        acc.z += (v.z > 0.f) ? s : 0.f;
        acc.w += (v.w > 0.f) ? s : 0.f;
    }

    __shared__ float4 hbuf[128];
    if (half) hbuf[t - 128] = acc;
    __syncthreads();
    if (!half) {
        const float4 h = hbuf[t];
        acc.x += h.x; acc.y += h.y; acc.z += h.z; acc.w += h.w;
        reinterpret_cast<float4*>(out)[u] = acc;    // single direct store
    }
}

extern "C" void kernel_launch(void* const* d_in, const int* in_sizes, int n_in,
                              void* d_out, int out_size, void* d_ws, size_t ws_size,
                              hipStream_t stream) {
    const float* prev = (const float*)d_in[0];
    const float* curr = (const float*)d_in[1];
    float* out     = (float*)d_out;
    float* partial = (float*)d_ws;   // 1024 floats, written before read

    count_pos_kernel<<<dim3(NB, NSLICE), 256, 0, stream>>>(curr, partial);
    corr_kernel<<<PREV_V4 / 128, 256, 0, stream>>>(prev, partial, out);
}

// Round 9
// 34.416 us; speedup vs baseline: 1.1075x; 1.1075x over previous
//
#include <hip/hip_runtime.h>

// out[chw] = sum_b (prev_x[b,chw] > 0) * popcount_pos(curr_x[b])
//   prev_x: [128, 256, 28, 28] f32, curr_x: [128, 512, 14, 14] f32
// All values integer <= 128*100352 < 2^24 -> exact in fp32 in any order.
//
// R9 = R6 (best, 29.89 us) + nontemporal loads/stores, now via clang
// ext_vector_type (R8 failed: the builtin rejects HIP_vector_type). Both
// input streams are read-exactly-once, so L1/L2 allocation is pure overhead;
// `nt` may lift the streaming service rate. Otherwise bit-identical to R6.
//  - R7 lesson: float4 pair-split w/ unroll 32 = register cliff (38 us).

typedef float v4f __attribute__((ext_vector_type(4)));
typedef float v2f __attribute__((ext_vector_type(2)));

constexpr int NB       = 128;
constexpr int CURR_CHW = 512 * 14 * 14;    // 100352 floats per batch
constexpr int PREV_CHW = 256 * 28 * 28;    // 200704 floats per batch
constexpr int CURR_V4  = CURR_CHW / 4;     // 25088 v4f per batch
constexpr int NSLICE   = 8;                // k1 slices per batch
constexpr int SLICE_V4 = CURR_V4 / NSLICE; // 3136 v4f per (batch, slice)
constexpr int PREV_V2  = PREV_CHW / 2;     // 100352 v2f columns

// Kernel 1: partial positive-count of curr_x. grid = (128, 8) = 1024 blocks.
__global__ void __launch_bounds__(256)
count_pos_kernel(const float* __restrict__ curr, float* __restrict__ partial) {
    const int b = blockIdx.x, q = blockIdx.y;
    const v4f* p = reinterpret_cast<const v4f*>(curr)
                   + (size_t)b * CURR_V4 + (size_t)q * SLICE_V4;
    int cnt = 0;
    for (int i = threadIdx.x; i < SLICE_V4; i += 256) {
        const v4f v = __builtin_nontemporal_load(&p[i]);
        cnt += (v.x > 0.f) + (v.y > 0.f) + (v.z > 0.f) + (v.w > 0.f);
    }
    #pragma unroll
    for (int off = 32; off > 0; off >>= 1)
        cnt += __shfl_down(cnt, off, 64);
    __shared__ int wsum[4];
    if ((threadIdx.x & 63) == 0) wsum[threadIdx.x >> 6] = cnt;
    __syncthreads();
    if (threadIdx.x == 0)
        partial[q * NB + b] = (float)(wsum[0] + wsum[1] + wsum[2] + wsum[3]);
}

// Kernel 2: out[chw] = sum_b (prev>0) * s_sum[b]. One v2f column per thread,
// 392 blocks x 256 threads = exact cover, unroll 32, nt loads + nt store.
__global__ void __launch_bounds__(256)
corr_kernel(const float* __restrict__ prev, const float* __restrict__ partial,
            float* __restrict__ out) {
    __shared__ float s_sum[NB];
    const int t = threadIdx.x;
    if (t < NB) {
        float s = 0.f;
        #pragma unroll
        for (int q = 0; q < NSLICE; ++q)
            s += partial[q * NB + t];
        s_sum[t] = s;
    }
    __syncthreads();

    const int u = blockIdx.x * 256 + t;          // v2f column, 0..100351
    const v2f* pv = reinterpret_cast<const v2f*>(prev) + u;

    v2f acc = (v2f)(0.f);
    #pragma unroll 32
    for (int b = 0; b < NB; ++b) {
        const v2f v = __builtin_nontemporal_load(&pv[(size_t)b * PREV_V2]);
        const float s = s_sum[b];                  // wave-uniform broadcast
        acc.x += (v.x > 0.f) ? s : 0.f;
        acc.y += (v.y > 0.f) ? s : 0.f;
    }
    __builtin_nontemporal_store(acc, &reinterpret_cast<v2f*>(out)[u]);
}

extern "C" void kernel_launch(void* const* d_in, const int* in_sizes, int n_in,
                              void* d_out, int out_size, void* d_ws, size_t ws_size,
                              hipStream_t stream) {
    const float* prev = (const float*)d_in[0];
    const float* curr = (const float*)d_in[1];
    float* out     = (float*)d_out;
    float* partial = (float*)d_ws;   // 1024 floats, written before read

    count_pos_kernel<<<dim3(NB, NSLICE), 256, 0, stream>>>(curr, partial);
    corr_kernel<<<PREV_V2 / 256, 256, 0, stream>>>(prev, partial, out);
}

// Round 10
// 29.935 us; speedup vs baseline: 1.2732x; 1.1497x over previous
//
#include <hip/hip_runtime.h>

// out[chw] = sum_b (prev_x[b,chw] > 0) * popcount_pos(curr_x[b])
//   prev_x: [128, 256, 28, 28] f32, curr_x: [128, 512, 14, 14] f32
// All values integer <= 128*100352 < 2^24 -> exact in fp32 in any order.
//
// R10: clean request-size isolation in k2. Same shape as R6 (392 blk x 256
// thr, 256 B in flight/thread), but thread pair (t, t^1) shares one float4
// column: even lane = batches 0..63, odd = 64..127 -> 16 B/lane requests
// (half the wave-request count per byte vs R6's float2), combine via 4
// __shfl_xor, even lane stores. No pair-split register cliff (R7's mistake:
// 512 B in flight), no idle epilogue half.
//  - R9 lesson: nontemporal bypasses L3 residency -> -15%. Regular loads.

constexpr int NB       = 128;
constexpr int CURR_CHW = 512 * 14 * 14;    // 100352 floats per batch
constexpr int PREV_CHW = 256 * 28 * 28;    // 200704 floats per batch
constexpr int CURR_V4  = CURR_CHW / 4;     // 25088 float4 per batch
constexpr int NSLICE   = 8;                // k1 slices per batch
constexpr int SLICE_V4 = CURR_V4 / NSLICE; // 3136 float4 per (batch, slice)
constexpr int PREV_V4  = PREV_CHW / 4;     // 50176 float4 columns

// Kernel 1: partial positive-count of curr_x. grid = (128, 8) = 1024 blocks.
__global__ void __launch_bounds__(256)
count_pos_kernel(const float* __restrict__ curr, float* __restrict__ partial) {
    const int b = blockIdx.x, q = blockIdx.y;
    const float4* p = reinterpret_cast<const float4*>(curr)
                      + (size_t)b * CURR_V4 + (size_t)q * SLICE_V4;
    int cnt = 0;
    for (int i = threadIdx.x; i < SLICE_V4; i += 256) {
        const float4 v = p[i];
        cnt += (v.x > 0.f) + (v.y > 0.f) + (v.z > 0.f) + (v.w > 0.f);
    }
    #pragma unroll
    for (int off = 32; off > 0; off >>= 1)
        cnt += __shfl_down(cnt, off, 64);
    __shared__ int wsum[4];
    if ((threadIdx.x & 63) == 0) wsum[threadIdx.x >> 6] = cnt;
    __syncthreads();
    if (threadIdx.x == 0)
        partial[q * NB + b] = (float)(wsum[0] + wsum[1] + wsum[2] + wsum[3]);
}

// Kernel 2: out[chw] = sum_b (prev>0) * s_sum[b].
// 392 blocks x 256 threads. Thread pair (t even/odd) shares float4 column
// col = blk*128 + t/2; even lane sums batches 0..63, odd 64..127.
// 16 B/lane coalesced loads, unroll 16 -> 256 B in flight per thread.
__global__ void __launch_bounds__(256)
corr_kernel(const float* __restrict__ prev, const float* __restrict__ partial,
            float* __restrict__ out) {
    __shared__ float s_sum[NB];
    const int t = threadIdx.x;
    if (t < NB) {
        float s = 0.f;
        #pragma unroll
        for (int q = 0; q < NSLICE; ++q)
            s += partial[q * NB + t];
        s_sum[t] = s;
    }
    __syncthreads();

    const int col  = blockIdx.x * 128 + (t >> 1);   // float4 column, 0..50175
    const int half = t & 1;                         // batch half (lane parity)
    const float4* pv = reinterpret_cast<const float4*>(prev)
                       + (size_t)(half * 64) * PREV_V4 + col;
    const float* sh = s_sum + half * 64;

    float4 acc = make_float4(0.f, 0.f, 0.f, 0.f);
    #pragma unroll 16
    for (int b = 0; b < 64; ++b) {
        const float4 v = pv[(size_t)b * PREV_V4];   // 16 B/lane coalesced
        const float s = sh[b];                      // 2 LDS addrs/wave, no conflict
        acc.x += (v.x > 0.f) ? s : 0.f;
        acc.y += (v.y > 0.f) ? s : 0.f;
        acc.z += (v.z > 0.f) ? s : 0.f;
        acc.w += (v.w > 0.f) ? s : 0.f;
    }
    // combine lane pair (t, t^1): both halves of the same column
    acc.x += __shfl_xor(acc.x, 1, 64);
    acc.y += __shfl_xor(acc.y, 1, 64);
    acc.z += __shfl_xor(acc.z, 1, 64);
    acc.w += __shfl_xor(acc.w, 1, 64);
    if (!half)
        reinterpret_cast<float4*>(out)[col] = acc;  // even lanes: 512 B/wave
}

extern "C" void kernel_launch(void* const* d_in, const int* in_sizes, int n_in,
                              void* d_out, int out_size, void* d_ws, size_t ws_size,
                              hipStream_t stream) {
    const float* prev = (const float*)d_in[0];
    const float* curr = (const float*)d_in[1];
    float* out     = (float*)d_out;
    float* partial = (float*)d_ws;   // 1024 floats, written before read

    count_pos_kernel<<<dim3(NB, NSLICE), 256, 0, stream>>>(curr, partial);
    corr_kernel<<<PREV_V4 / 128, 256, 0, stream>>>(prev, partial, out);
}